// Round 11
// baseline (668.106 us; speedup 1.0000x reference)
//
#include <hip/hip_runtime.h>

// AssociationLayer: masked Sinkhorn (100 iters) + mutual-argmax assignment.
// R16 = R15 with MFMA fed DIRECTLY from AGPRs (no agpr_load round-trip).
//  R15 post-mortem: AGPR residency worked (LDS 136->5.6 KB, dur flat) but
//  agpr_load's 32 transient V-regs + KA's 32 persistent V-regs overflowed
//  the 64-V half of the 1024-thread budget -> ~100 MB V-side scratch
//  (WRITE +63, FETCH +34 vs R13).
//  R16: gfx950 MFMA reads A/B from AGPR directly (cdna4_isa SS10). Inline asm
//  "v_mfma_f32_16x16x32_bf16 %0,%1,%2,%0" with "a" operands; KA+KB = 64 A
//  exactly; V side holds only transients (~55 < 64). Hazard guards (asm is
//  opaque to the hazard recognizer): s_nop 1 before each chain (VALU write ->
//  MFMA srcC), 2x s_nop 7 after (MFMA write -> VALU read); same-D MFMA
//  chaining needs no nops. Epilogue never touches the A-resident panels --
//  it recomputes K from aff (L2-hot; __expf+f2bf deterministic -> bitwise-
//  identical T) one panel at a time, so the allocator has no V uses to
//  pessimize. Loop LDS: 256 b128 broadcasts/CU/iter (VF+UF only).
//  absmax ~1.0 (tie flips from bf16 K) vs threshold 4.92.

#define T_MAX   256
#define L_FLAT  (257 * 257)
#define N_ITERS 100
#define LAMBDA_F 10.0f
#define EPS_F    1e-12f

#define ROR1 0x121
#define ROR2 0x122
#define ROR4 0x124
#define ROR8 0x128

typedef short bf8   __attribute__((ext_vector_type(8)));  // 8 bf16 = 4 regs
typedef float f32x4 __attribute__((ext_vector_type(4)));

struct F4 { float a, b, c, d; };   // 16B payload, 4B-aligned packed store

// MFMA with AGPR-resident operands (gfx950: A/B from VGPR or AGPR).
__device__ __forceinline__ void mfma_AV(f32x4& d, const bf8& a, const bf8& b) {
    asm volatile("v_mfma_f32_16x16x32_bf16 %0, %1, %2, %0"
                 : "+v"(d) : "a"(a), "v"(b));
}
__device__ __forceinline__ void mfma_VA(f32x4& d, const bf8& a, const bf8& b) {
    asm volatile("v_mfma_f32_16x16x32_bf16 %0, %1, %2, %0"
                 : "+v"(d) : "v"(a), "a"(b));
}
__device__ __forceinline__ void mfma_pre()  { asm volatile("s_nop 1"); }
__device__ __forceinline__ void mfma_post() { asm volatile("s_nop 7\n\ts_nop 7"); }

template<int CTRL>
__device__ __forceinline__ float dpp_addf(float x) {
    int t = __builtin_amdgcn_update_dpp(0, __float_as_int(x), CTRL, 0xF, 0xF, true);
    return x + __int_as_float(t);
}
__device__ __forceinline__ float swz16_addf(float x) {
    return x + __int_as_float(__builtin_amdgcn_ds_swizzle(__float_as_int(x), 0x401F));
}
__device__ __forceinline__ float swz16_maxf(float x) {
    return fmaxf(x, __int_as_float(__builtin_amdgcn_ds_swizzle(__float_as_int(x), 0x401F)));
}
__device__ __forceinline__ int swz16_ori(int x) {
    return x | __builtin_amdgcn_ds_swizzle(x, 0x401F);
}
__device__ __forceinline__ float fast_rcp(float x) {
#if __has_builtin(__builtin_amdgcn_rcpf)
    return __builtin_amdgcn_rcpf(x);
#else
    return 1.0f / x;
#endif
}
__device__ __forceinline__ unsigned short f2bf(float x) {   // RNE f32->bf16
    unsigned u = __float_as_uint(x);
    return (unsigned short)((u + 0x7FFFu + ((u >> 16) & 1u)) >> 16);
}
__device__ __forceinline__ float bf2f(short s) {            // exact bf16->f32
    return __uint_as_float(((unsigned)(unsigned short)s) << 16);
}

__global__ __launch_bounds__(1024, 1) void assoc_sinkhorn_kernel(
    const float* __restrict__ aff,
    const int*   __restrict__ ndet,
    const int*   __restrict__ ntrk,
    float*       __restrict__ out_t,
    float*       __restrict__ out_a)
{
    const int b   = blockIdx.x;
    const int nd  = ndet[b];
    const int nt  = ntrk[b];
    const int tid = threadIdx.x;
    const int w   = tid >> 6;     // wave 0..15 -> rows/cols 16w..16w+15
    const int l   = tid & 63;
    const int lr  = l & 15;       // m/n index within 16x16 tile
    const int lk  = l >> 4;       // k-group 0..3

    __shared__ __align__(16) unsigned short u_bf[256];
    __shared__ __align__(16) unsigned short v_bf[256];
    __shared__ __align__(16) float u_f[256];
    __shared__ __align__(16) float v_f[256];
    __shared__ __align__(16) float SuAcc[2];   // ping-pong cross-wave sums
    __shared__ __align__(16) float SvAcc[2];
    __shared__ __align__(16) float rm_s[256];
    __shared__ __align__(16) float cm_s[256];

    const float ndf = (float)nd;
    const float ntf = (float)nt;

    // ---------------- prologue: build bf16 K panels into AGPRs ----------------
    // KA_A: row-panel (A-op): row 16w+lr, cols 32t+8lk+j
    // KB_A: col-panel (B-op): col 16w+lr, rows 32t+8lk+j
    // Only uses are "a"-constrained MFMA operands -> allocator keeps A-class.
    bf8 KA_A[8];
    bf8 KB_A[8];
    const float* Ab = aff + (size_t)b * (T_MAX * T_MAX);

    const int myrow = 16 * w + lr;
    const int mycol = 16 * w + lr;

    {
        const bool rv = (myrow < nt);
        const float* rp = Ab + (size_t)myrow * T_MAX;
        #pragma unroll
        for (int t = 0; t < 8; ++t) {
            const int c0 = 32 * t + 8 * lk;
            const float4 x0 = *reinterpret_cast<const float4*>(rp + c0);
            const float4 x1 = *reinterpret_cast<const float4*>(rp + c0 + 4);
            const float e[8] = {x0.x, x0.y, x0.z, x0.w, x1.x, x1.y, x1.z, x1.w};
            bf8 kk;
            #pragma unroll
            for (int j = 0; j < 8; ++j) {
                const float val = (rv && (c0 + j) < nd) ? __expf(LAMBDA_F * e[j]) : 0.0f;
                kk[j] = (short)f2bf(val);
            }
            KA_A[t] = kk;
        }
    }
    {
        const bool cv = (mycol < nd);
        #pragma unroll
        for (int t = 0; t < 8; ++t) {
            const int r0 = 32 * t + 8 * lk;
            bf8 kk;
            #pragma unroll
            for (int j = 0; j < 8; ++j) {
                const float x = Ab[(size_t)(r0 + j) * T_MAX + mycol];
                const float val = (cv && (r0 + j) < nt) ? __expf(LAMBDA_F * x) : 0.0f;
                kk[j] = (short)f2bf(val);
            }
            KB_A[t] = kk;
        }
    }

    if (tid < 256) v_bf[tid] = (tid < nd) ? f2bf(1.0f) : (unsigned short)0;
    if (tid == 0) {
        SuAcc[0] = 0.0f; SuAcc[1] = 0.0f;
        SvAcc[0] = ndf;  SvAcc[1] = 0.0f;   // initial Sv = nd (v=1 on valid cols)
    }
    __syncthreads();

    float vbd = 1.0f;   // v[nd]
    float ubd = 0.0f;   // u[nt]

    const int r_a0 = 16 * w + 4 * lk;   // base row of this lane's acc quad
    float u4[4] = {0.f, 0.f, 0.f, 0.f};
    float v0 = 0.0f;

    // loop-invariant validity masks
    float rvm[4];
    #pragma unroll
    for (int q = 0; q < 4; ++q) rvm[q] = ((r_a0 + q) < nt) ? 1.0f : 0.0f;
    const float cvm = (mycol < nd) ? 1.0f : 0.0f;

    // ---------------- Sinkhorn iterations ----------------
    for (int it = 0; it < N_ITERS; ++it) {
        const int p = it & 1;
        const float Sv = SvAcc[p];   // broadcast read; consumed below (slack)

        // ---- dir1: p = K @ v (A-operand from AGPR; VF broadcast) ----
        f32x4 acc = {0.0f, 0.0f, 0.0f, 0.0f};
        mfma_pre();
        #pragma unroll
        for (int t = 0; t < 8; ++t) {
            const bf8 VF = *reinterpret_cast<const bf8*>(&v_bf[32 * t + 8 * lk]);
            mfma_AV(acc, KA_A[t], VF);
        }
        mfma_post();

        const float vbdE = vbd + EPS_F;
        #pragma unroll
        for (int q = 0; q < 4; ++q)
            u4[q] = rvm[q] * fast_rcp(acc[q] + vbdE);

        // wave Sigma(u): sum 4 quads, fold lk groups (x16, x32), one atomic
        {
            float su = (u4[0] + u4[1]) + (u4[2] + u4[3]);
            su = swz16_addf(su);
            su += __shfl_xor(su, 32, 64);
            if (l == 0) atomicAdd(&SuAcc[p], su);
        }
        if (tid == 0) SuAcc[p ^ 1] = 0.0f;   // stale slot: last read prev iter

        // publish u as bf16; writers: lr==0 lanes (4 rows each)
        if (lr == 0) {
            const unsigned p01 = (unsigned)f2bf(u4[0]) | ((unsigned)f2bf(u4[1]) << 16);
            const unsigned p23 = (unsigned)f2bf(u4[2]) | ((unsigned)f2bf(u4[3]) << 16);
            *reinterpret_cast<uint2*>(&u_bf[r_a0]) = uint2{p01, p23};
        }
        __syncthreads();   // barrier A: u + SuAcc[p] published

        const float Su = SuAcc[p];
        const float ubd_new = ndf * fast_rcp(Sv + vbd + EPS_F);
        const float vbd_new = ntf * fast_rcp(Su + ubd_new + EPS_F);

        // ---- dir2: q = K^T @ u (B-operand from AGPR; UF broadcast) ----
        f32x4 qa = {0.0f, 0.0f, 0.0f, 0.0f};
        mfma_pre();
        #pragma unroll
        for (int t = 0; t < 8; ++t) {
            const bf8 UF = *reinterpret_cast<const bf8*>(&u_bf[32 * t + 8 * lk]);
            mfma_VA(qa, UF, KB_A[t]);
        }
        mfma_post();

        const float ubdE = ubd_new + EPS_F;
        v0 = cvm * fast_rcp(qa[0] + ubdE);

        // wave Sigma(v) over its 16 cols (varies over lr): DPP fold + atomic
        {
            float sv = v0;
            sv = dpp_addf<ROR1>(sv);
            sv = dpp_addf<ROR2>(sv);
            sv = dpp_addf<ROR4>(sv);
            sv = dpp_addf<ROR8>(sv);
            if (l == 0) atomicAdd(&SvAcc[p ^ 1], sv);
        }
        if (tid == 0) SvAcc[p] = 0.0f;   // stale slot: last read this dir1
        if (lk == 0) v_bf[mycol] = f2bf(v0);
        ubd = ubd_new;
        vbd = vbd_new;
        __syncthreads();   // barrier B: v + SvAcc[p^1] published
    }

    // ---- publish final u, v in f32 for the epilogue ----
    if (lr == 0) {
        f32x4 uf = {u4[0], u4[1], u4[2], u4[3]};
        *reinterpret_cast<f32x4*>(&u_f[r_a0]) = uf;
    }
    if (lk == 0) v_f[mycol] = v0;
    __syncthreads();

    // ================= epilogue =================
    // K recomputed from aff (L2-hot; __expf+f2bf deterministic) so the
    // AGPR panels have zero VALU uses. One panel live at a time.
    // T = (u*k)*v, identical mul order everywhere -> bitwise-consistent
    // mutual-argmax equality tests.
    const bool rv_e = (myrow < nt);
    const bool cv_e = (mycol < nd);

    float rm;   // E1: rowmax (row panel recompute #1)
    {
        const float ur = u_f[myrow];
        const float* rp = Ab + (size_t)myrow * T_MAX;
        float mm = 0.0f;
        #pragma unroll
        for (int t = 0; t < 8; ++t) {
            const int c0 = 32 * t + 8 * lk;
            const float4 x0 = *reinterpret_cast<const float4*>(rp + c0);
            const float4 x1 = *reinterpret_cast<const float4*>(rp + c0 + 4);
            const float e[8] = {x0.x, x0.y, x0.z, x0.w, x1.x, x1.y, x1.z, x1.w};
            const f32x4 va = *reinterpret_cast<const f32x4*>(&v_f[c0]);
            const f32x4 vb = *reinterpret_cast<const f32x4*>(&v_f[c0 + 4]);
            const float vj[8] = {va[0], va[1], va[2], va[3], vb[0], vb[1], vb[2], vb[3]};
            #pragma unroll
            for (int j = 0; j < 8; ++j) {
                const float kv = (rv_e && (c0 + j) < nd) ? __expf(LAMBDA_F * e[j]) : 0.0f;
                const float tv = ur * bf2f((short)f2bf(kv)) * vj[j];
                mm = fmaxf(mm, tv);
            }
        }
        mm = swz16_maxf(mm);
        mm = fmaxf(mm, __shfl_xor(mm, 32, 64));
        rm = mm;
        if (lk == 0) rm_s[myrow] = mm;
    }
    float cmv;  // E2: colmax (col panel recompute #1)
    {
        const float vc = v_f[mycol];
        float mm = 0.0f;
        #pragma unroll
        for (int t = 0; t < 8; ++t) {
            const int rb = 32 * t + 8 * lk;
            const f32x4 ua = *reinterpret_cast<const f32x4*>(&u_f[rb]);
            const f32x4 ub = *reinterpret_cast<const f32x4*>(&u_f[rb + 4]);
            const float uj[8] = {ua[0], ua[1], ua[2], ua[3], ub[0], ub[1], ub[2], ub[3]};
            #pragma unroll
            for (int j = 0; j < 8; ++j) {
                const float x = Ab[(size_t)(rb + j) * T_MAX + mycol];
                const float kv = (cv_e && (rb + j) < nt) ? __expf(LAMBDA_F * x) : 0.0f;
                const float tv = uj[j] * bf2f((short)f2bf(kv)) * vc;
                mm = fmaxf(mm, tv);
            }
        }
        mm = swz16_maxf(mm);
        mm = fmaxf(mm, __shfl_xor(mm, 32, 64));
        cmv = mm;
        if (lk == 0) cm_s[mycol] = mm;
    }
    __syncthreads();   // rm_s / cm_s published

    float* Ot = out_t + (size_t)b * L_FLAT;
    float* Oa = out_a + (size_t)b * L_FLAT;
    const int stride = nd + 1;

    // E3: births row (col panel recompute #2) + corner
    {
        const float vc = v_f[mycol];
        int has = 0;
        #pragma unroll
        for (int t = 0; t < 8; ++t) {
            const int rb = 32 * t + 8 * lk;
            const f32x4 ua = *reinterpret_cast<const f32x4*>(&u_f[rb]);
            const f32x4 ub = *reinterpret_cast<const f32x4*>(&u_f[rb + 4]);
            const f32x4 ra = *reinterpret_cast<const f32x4*>(&rm_s[rb]);
            const f32x4 rb4 = *reinterpret_cast<const f32x4*>(&rm_s[rb + 4]);
            const float uj[8] = {ua[0], ua[1], ua[2], ua[3], ub[0], ub[1], ub[2], ub[3]};
            const float rj[8] = {ra[0], ra[1], ra[2], ra[3], rb4[0], rb4[1], rb4[2], rb4[3]};
            #pragma unroll
            for (int j = 0; j < 8; ++j) {
                const int rowj = rb + j;
                const float x = Ab[(size_t)rowj * T_MAX + mycol];
                const float kv = (cv_e && rowj < nt) ? __expf(LAMBDA_F * x) : 0.0f;
                const float tv = uj[j] * bf2f((short)f2bf(kv)) * vc;
                const bool bit = (rowj < nt) && cv_e && (tv == rj[j]) && (tv == cmv);
                has |= bit ? 1 : 0;
            }
        }
        has = swz16_ori(has);
        has |= __shfl_xor(has, 32, 64);
        if (lk == 0 && cv_e) {
            const int kk = nt * stride + mycol;
            Ot[kk] = ubd * vc;
            Oa[kk] = has ? 0.0f : 1.0f;
        }
    }
    if (tid == 0) {
        const int kk = nt * stride + nd;
        Ot[kk] = ubd * vbd;
        Oa[kk] = 0.0f;
    }

    // E4: interior + deaths (row panel recompute #2, 16B-packed stores)
    {
        const float ur = u_f[myrow];
        const float* rp = Ab + (size_t)myrow * T_MAX;
        int has = 0;
        #pragma unroll
        for (int t = 0; t < 8; ++t) {
            const int cb = 32 * t + 8 * lk;
            const float4 x0 = *reinterpret_cast<const float4*>(rp + cb);
            const float4 x1 = *reinterpret_cast<const float4*>(rp + cb + 4);
            const float e[8] = {x0.x, x0.y, x0.z, x0.w, x1.x, x1.y, x1.z, x1.w};
            const f32x4 va  = *reinterpret_cast<const f32x4*>(&v_f[cb]);
            const f32x4 vb  = *reinterpret_cast<const f32x4*>(&v_f[cb + 4]);
            const f32x4 ca  = *reinterpret_cast<const f32x4*>(&cm_s[cb]);
            const f32x4 cb4 = *reinterpret_cast<const f32x4*>(&cm_s[cb + 4]);
            const float vj[8] = {va[0], va[1], va[2], va[3], vb[0], vb[1], vb[2], vb[3]};
            const float cj[8] = {ca[0], ca[1], ca[2], ca[3], cb4[0], cb4[1], cb4[2], cb4[3]};
            float tvs[8];
            float abs_[8];
            #pragma unroll
            for (int j = 0; j < 8; ++j) {
                const float kv = (rv_e && (cb + j) < nd) ? __expf(LAMBDA_F * e[j]) : 0.0f;
                const float tv = ur * bf2f((short)f2bf(kv)) * vj[j];
                const bool bit = rv_e && ((cb + j) < nd) && (tv == rm) && (tv == cj[j]);
                tvs[j] = tv; abs_[j] = bit ? 1.0f : 0.0f;
                has |= bit ? 1 : 0;
            }
            if (rv_e) {
                float* OtR = Ot + (size_t)myrow * stride;
                float* OaR = Oa + (size_t)myrow * stride;
                #pragma unroll
                for (int g = 0; g < 2; ++g) {
                    const int c0 = cb + 4 * g;
                    if (c0 + 3 < nd) {
                        F4 ot = {tvs[4*g], tvs[4*g+1], tvs[4*g+2], tvs[4*g+3]};
                        F4 oa = {abs_[4*g], abs_[4*g+1], abs_[4*g+2], abs_[4*g+3]};
                        *reinterpret_cast<F4*>(OtR + c0) = ot;
                        *reinterpret_cast<F4*>(OaR + c0) = oa;
                    } else {
                        #pragma unroll
                        for (int j = 0; j < 4; ++j) {
                            if (c0 + j < nd) {
                                OtR[c0 + j] = tvs[4*g + j];
                                OaR[c0 + j] = abs_[4*g + j];
                            }
                        }
                    }
                }
            }
        }
        has = swz16_ori(has);
        has |= __shfl_xor(has, 32, 64);
        if (lk == 0 && rv_e) {
            const int kk = myrow * stride + nd;
            Ot[kk] = ur * vbd;
            Oa[kk] = has ? 0.0f : 1.0f;
        }
    }

    // zero-fill padding [length, L_FLAT)
    const int length = (nt + 1) * stride;
    for (int k = length + tid; k < L_FLAT; k += 1024) {
        Ot[k] = 0.0f;
        Oa[k] = 0.0f;
    }
}

extern "C" void kernel_launch(void* const* d_in, const int* in_sizes, int n_in,
                              void* d_out, int out_size, void* d_ws, size_t ws_size,
                              hipStream_t stream)
{
    const float* aff  = (const float*)d_in[0];
    const int*   ndet = (const int*)d_in[1];
    const int*   ntrk = (const int*)d_in[2];
    const int    Bn   = in_sizes[1];
    float* out_t = (float*)d_out;
    float* out_a = out_t + (size_t)Bn * L_FLAT;
    assoc_sinkhorn_kernel<<<dim3(Bn), dim3(1024), 0, stream>>>(aff, ndet, ntrk, out_t, out_a);
}

// Round 12
// 392.395 us; speedup vs baseline: 1.7026x; 1.7026x over previous
//
#include <hip/hip_runtime.h>

// AssociationLayer: masked Sinkhorn (100 iters) + mutual-argmax assignment.
// R17 = R13 verbatim (verified best: 255 us kernel / 392 us harness).
//  Session evidence bracket:
//   - R13 (this): KA regs + K^T fragment-linear LDS + ping-pong Su/Sv
//     atomics = 255 us. WRITE ~200 MB (output-only), conflicts 0.
//   - R15 (KB->AGPR via accvgpr round-trip): removed 128/384 LDS reads/iter,
//     time FLAT (264) -> loop is NOT marginally LDS-issue-bound.
//   - R14 (dir2 on VALU): 357 us. R16 (MFMA direct from AGPR asm): 542 us,
//     545 MB scratch -> this compiler will not hold persistent panels in
//     AGPRs without copies/spill. Both falsified.
//  Residual bound: serial chain (barrier -> broadcast -> 8 chained MFMA ->
//  rcp -> cross-lane reduce -> atomic -> barrier) x 200 barriers; no pipe
//  saturated (VALU 37 / MFMA 17 / HBM 14 / conflicts 0) -> latency-bound.
//  Structure:
//   - 1024 thr / 16 waves; wave w owns rows+cols 16w..16w+15.
//   - dir1 (K@v): MFMA, KA in VGPRs, VF = LDS broadcast of v (bf16).
//   - dir2 (K^T@u): MFMA, B-frags from KTL[w][t][lane][8bf16] in LDS --
//     lane-linear (each lane reads only what it wrote): stride-1
//     ds_read/write_b128, zero bank conflicts by construction.
//   - cross-wave Su/Sv: one ds atomicAdd per wave into ping-pong slots;
//     stale slot cleared by tid 0 one phase after last read.
//   - epilogue: identical (u*k)*v mul order + identical bf16 K bits on both
//     panels -> bitwise-consistent mutual-argmax; 16B packed interior stores.
//  absmax ~1.0 (argmax tie flips from bf16 K) vs threshold 4.92.

#define T_MAX   256
#define L_FLAT  (257 * 257)
#define N_ITERS 100
#define LAMBDA_F 10.0f
#define EPS_F    1e-12f

#define ROR1 0x121
#define ROR2 0x122
#define ROR4 0x124
#define ROR8 0x128

typedef short bf8   __attribute__((ext_vector_type(8)));  // 8 bf16 = 4 VGPRs
typedef float f32x4 __attribute__((ext_vector_type(4)));

struct F4 { float a, b, c, d; };   // 16B payload, 4B-aligned packed store

template<int CTRL>
__device__ __forceinline__ float dpp_addf(float x) {
    int t = __builtin_amdgcn_update_dpp(0, __float_as_int(x), CTRL, 0xF, 0xF, true);
    return x + __int_as_float(t);
}
__device__ __forceinline__ float swz16_addf(float x) {
    return x + __int_as_float(__builtin_amdgcn_ds_swizzle(__float_as_int(x), 0x401F));
}
__device__ __forceinline__ float swz16_maxf(float x) {
    return fmaxf(x, __int_as_float(__builtin_amdgcn_ds_swizzle(__float_as_int(x), 0x401F)));
}
__device__ __forceinline__ int swz16_ori(int x) {
    return x | __builtin_amdgcn_ds_swizzle(x, 0x401F);
}
__device__ __forceinline__ float fast_rcp(float x) {
#if __has_builtin(__builtin_amdgcn_rcpf)
    return __builtin_amdgcn_rcpf(x);
#else
    return 1.0f / x;
#endif
}
__device__ __forceinline__ unsigned short f2bf(float x) {   // RNE f32->bf16
    unsigned u = __float_as_uint(x);
    return (unsigned short)((u + 0x7FFFu + ((u >> 16) & 1u)) >> 16);
}
__device__ __forceinline__ float bf2f(short s) {            // exact bf16->f32
    return __uint_as_float(((unsigned)(unsigned short)s) << 16);
}

__global__ __launch_bounds__(1024, 1) void assoc_sinkhorn_kernel(
    const float* __restrict__ aff,
    const int*   __restrict__ ndet,
    const int*   __restrict__ ntrk,
    float*       __restrict__ out_t,
    float*       __restrict__ out_a)
{
    const int b   = blockIdx.x;
    const int nd  = ndet[b];
    const int nt  = ntrk[b];
    const int tid = threadIdx.x;
    const int w   = tid >> 6;     // wave 0..15 -> rows/cols 16w..16w+15
    const int l   = tid & 63;
    const int lr  = l & 15;       // m/n index within 16x16 tile
    const int lk  = l >> 4;       // k-group 0..3

    // K^T fragment-linear: [w][t][lane][8 bf16] -> 16B/lane, stride-1 b128
    __shared__ __align__(16) unsigned short KTL[16 * 8 * 64 * 8];   // 128 KB
    __shared__ __align__(16) unsigned short u_bf[256];
    __shared__ __align__(16) unsigned short v_bf[256];
    __shared__ __align__(16) float u_f[256];
    __shared__ __align__(16) float v_f[256];
    __shared__ __align__(16) float SuAcc[2];   // ping-pong cross-wave sums
    __shared__ __align__(16) float SvAcc[2];
    __shared__ __align__(16) float rm_s[256];
    __shared__ __align__(16) float cm_s[256];

    const float ndf = (float)nd;
    const float ntf = (float)nt;

    // ---------------- prologue: build bf16 K fragments ----------------
    bf8 KA[8];   // row-panel (A-op): row 16w+lr, cols 32t+8lk+j
    const float* Ab = aff + (size_t)b * (T_MAX * T_MAX);

    const int myrow = 16 * w + lr;
    const int mycol = 16 * w + lr;
    unsigned short* myKTL = &KTL[(size_t)(w * 8 * 64 + l) * 8];   // + t*512

    {
        const bool rv = (myrow < nt);
        const float* rp = Ab + (size_t)myrow * T_MAX;
        #pragma unroll
        for (int t = 0; t < 8; ++t) {
            const int c0 = 32 * t + 8 * lk;
            const float4 x0 = *reinterpret_cast<const float4*>(rp + c0);
            const float4 x1 = *reinterpret_cast<const float4*>(rp + c0 + 4);
            const float e[8] = {x0.x, x0.y, x0.z, x0.w, x1.x, x1.y, x1.z, x1.w};
            bf8 kk;
            #pragma unroll
            for (int j = 0; j < 8; ++j) {
                const float val = (rv && (c0 + j) < nd) ? __expf(LAMBDA_F * e[j]) : 0.0f;
                kk[j] = (short)f2bf(val);
            }
            KA[t] = kk;
        }
    }
    {
        // col-panel (B-op): col 16w+lr, rows 32t+8lk+j -> straight to LDS
        const bool cv = (mycol < nd);
        #pragma unroll
        for (int t = 0; t < 8; ++t) {
            const int r0 = 32 * t + 8 * lk;
            bf8 kk;
            #pragma unroll
            for (int j = 0; j < 8; ++j) {
                const float x = Ab[(size_t)(r0 + j) * T_MAX + mycol];
                const float val = (cv && (r0 + j) < nt) ? __expf(LAMBDA_F * x) : 0.0f;
                kk[j] = (short)f2bf(val);
            }
            *reinterpret_cast<bf8*>(myKTL + t * 512) = kk;   // lane-linear b128
        }
    }

    if (tid < 256) v_bf[tid] = (tid < nd) ? f2bf(1.0f) : (unsigned short)0;
    if (tid == 0) {
        SuAcc[0] = 0.0f; SuAcc[1] = 0.0f;
        SvAcc[0] = ndf;  SvAcc[1] = 0.0f;   // initial Sv = nd (v=1 on valid cols)
    }
    __syncthreads();

    float vbd = 1.0f;   // v[nd]
    float ubd = 0.0f;   // u[nt]

    const int r_a0 = 16 * w + 4 * lk;   // base row of this lane's acc quad
    float u4[4] = {0.f, 0.f, 0.f, 0.f};
    float v0 = 0.0f;

    // loop-invariant validity masks (mul instead of cmp+cndmask in loop)
    float rvm[4];
    #pragma unroll
    for (int q = 0; q < 4; ++q) rvm[q] = ((r_a0 + q) < nt) ? 1.0f : 0.0f;
    const float cvm = (mycol < nd) ? 1.0f : 0.0f;

    // ---------------- Sinkhorn iterations ----------------
    for (int it = 0; it < N_ITERS; ++it) {
        const int p = it & 1;
        const float Sv = SvAcc[p];   // broadcast read; consumed below (slack)

        // ---- dir1: p = K @ v (KA regs; VF = broadcast of v) ----
        f32x4 acc = {0.0f, 0.0f, 0.0f, 0.0f};
        #pragma unroll
        for (int t = 0; t < 8; ++t) {
            const bf8 VF = *reinterpret_cast<const bf8*>(&v_bf[32 * t + 8 * lk]);
            acc = __builtin_amdgcn_mfma_f32_16x16x32_bf16(KA[t], VF, acc, 0, 0, 0);
        }

        const float vbdE = vbd + EPS_F;
        #pragma unroll
        for (int q = 0; q < 4; ++q)
            u4[q] = rvm[q] * fast_rcp(acc[q] + vbdE);

        // wave Sigma(u): sum 4 quads, fold lk groups (x16, x32), one atomic
        {
            float su = (u4[0] + u4[1]) + (u4[2] + u4[3]);
            su = swz16_addf(su);
            su += __shfl_xor(su, 32, 64);
            if (l == 0) atomicAdd(&SuAcc[p], su);
        }
        if (tid == 0) SuAcc[p ^ 1] = 0.0f;   // stale slot: last read prev iter

        // publish u as bf16; writers: lr==0 lanes (4 rows each)
        if (lr == 0) {
            const unsigned p01 = (unsigned)f2bf(u4[0]) | ((unsigned)f2bf(u4[1]) << 16);
            const unsigned p23 = (unsigned)f2bf(u4[2]) | ((unsigned)f2bf(u4[3]) << 16);
            *reinterpret_cast<uint2*>(&u_bf[r_a0]) = uint2{p01, p23};
        }
        __syncthreads();   // barrier A: u + SuAcc[p] published

        const float Su = SuAcc[p];   // one broadcast read (was 16-term tree)
        const float ubd_new = ndf * fast_rcp(Sv + vbd + EPS_F);
        const float vbd_new = ntf * fast_rcp(Su + ubd_new + EPS_F);

        // ---- dir2: q = K^T @ u (B-frags: lane-linear KTL reads) ----
        f32x4 qa = {0.0f, 0.0f, 0.0f, 0.0f};
        #pragma unroll
        for (int t = 0; t < 8; ++t) {
            const bf8 UF = *reinterpret_cast<const bf8*>(&u_bf[32 * t + 8 * lk]);
            const bf8 kb = *reinterpret_cast<const bf8*>(myKTL + t * 512);
            qa = __builtin_amdgcn_mfma_f32_16x16x32_bf16(UF, kb, qa, 0, 0, 0);
        }

        const float ubdE = ubd_new + EPS_F;
        v0 = cvm * fast_rcp(qa[0] + ubdE);

        // wave Sigma(v) over its 16 cols (varies over lr): DPP fold + atomic
        {
            float sv = v0;
            sv = dpp_addf<ROR1>(sv);
            sv = dpp_addf<ROR2>(sv);
            sv = dpp_addf<ROR4>(sv);
            sv = dpp_addf<ROR8>(sv);
            if (l == 0) atomicAdd(&SvAcc[p ^ 1], sv);
        }
        if (tid == 0) SvAcc[p] = 0.0f;   // stale slot: last read this dir1
        if (lk == 0) v_bf[mycol] = f2bf(v0);
        ubd = ubd_new;
        vbd = vbd_new;
        __syncthreads();   // barrier B: v + SvAcc[p^1] published
    }

    // ---- publish final u, v in f32 for the epilogue ----
    if (lr == 0) {
        f32x4 uf = {u4[0], u4[1], u4[2], u4[3]};
        *reinterpret_cast<f32x4*>(&u_f[r_a0]) = uf;
    }
    if (lk == 0) v_f[mycol] = v0;
    __syncthreads();

    // ================= epilogue =================
    // T = (u*k)*v with identical mul order on both panels -> bitwise-
    // consistent equality tests for mutual argmax.
    float rm;   // rowmax of this lane's row
    {
        const float ur = u_f[myrow];
        float mm = 0.0f;
        #pragma unroll
        for (int t = 0; t < 8; ++t) {
            const f32x4 va = *reinterpret_cast<const f32x4*>(&v_f[32 * t + 8 * lk]);
            const f32x4 vb = *reinterpret_cast<const f32x4*>(&v_f[32 * t + 8 * lk + 4]);
            const float vj[8] = {va[0], va[1], va[2], va[3], vb[0], vb[1], vb[2], vb[3]};
            #pragma unroll
            for (int j = 0; j < 8; ++j) {
                const float tv = ur * bf2f(KA[t][j]) * vj[j];
                mm = fmaxf(mm, tv);
            }
        }
        mm = swz16_maxf(mm);
        mm = fmaxf(mm, __shfl_xor(mm, 32, 64));
        rm = mm;
        if (lk == 0) rm_s[myrow] = mm;
    }
    float cmv;  // colmax of this lane's col
    {
        const float vc = v_f[mycol];
        float mm = 0.0f;
        #pragma unroll
        for (int t = 0; t < 8; ++t) {
            const int rb = 32 * t + 8 * lk;
            const bf8 kb = *reinterpret_cast<const bf8*>(myKTL + t * 512);
            const f32x4 ua = *reinterpret_cast<const f32x4*>(&u_f[rb]);
            const f32x4 ub = *reinterpret_cast<const f32x4*>(&u_f[rb + 4]);
            const float uj[8] = {ua[0], ua[1], ua[2], ua[3], ub[0], ub[1], ub[2], ub[3]};
            #pragma unroll
            for (int j = 0; j < 8; ++j) {
                const float tv = uj[j] * bf2f(kb[j]) * vc;
                mm = fmaxf(mm, tv);
            }
        }
        mm = swz16_maxf(mm);
        mm = fmaxf(mm, __shfl_xor(mm, 32, 64));
        cmv = mm;
        if (lk == 0) cm_s[mycol] = mm;
    }
    __syncthreads();   // rm_s / cm_s published

    float* Ot = out_t + (size_t)b * L_FLAT;
    float* Oa = out_a + (size_t)b * L_FLAT;
    const int stride = nd + 1;

    // births row (col-panel: col-has + write) + corner
    {
        const float vc = v_f[mycol];
        const bool cv = (mycol < nd);
        int has = 0;
        #pragma unroll
        for (int t = 0; t < 8; ++t) {
            const int rb = 32 * t + 8 * lk;
            const bf8 kb = *reinterpret_cast<const bf8*>(myKTL + t * 512);
            const f32x4 ua = *reinterpret_cast<const f32x4*>(&u_f[rb]);
            const f32x4 ub = *reinterpret_cast<const f32x4*>(&u_f[rb + 4]);
            const f32x4 ra = *reinterpret_cast<const f32x4*>(&rm_s[rb]);
            const f32x4 rb4 = *reinterpret_cast<const f32x4*>(&rm_s[rb + 4]);
            const float uj[8] = {ua[0], ua[1], ua[2], ua[3], ub[0], ub[1], ub[2], ub[3]};
            const float rj[8] = {ra[0], ra[1], ra[2], ra[3], rb4[0], rb4[1], rb4[2], rb4[3]};
            #pragma unroll
            for (int j = 0; j < 8; ++j) {
                const int rowj = rb + j;
                const float tv = uj[j] * bf2f(kb[j]) * vc;
                const bool bit = (rowj < nt) && cv && (tv == rj[j]) && (tv == cmv);
                has |= bit ? 1 : 0;
            }
        }
        has = swz16_ori(has);
        has |= __shfl_xor(has, 32, 64);
        if (lk == 0 && cv) {
            const int kk = nt * stride + mycol;
            Ot[kk] = ubd * vc;
            Oa[kk] = has ? 0.0f : 1.0f;
        }
    }
    if (tid == 0) {
        const int kk = nt * stride + nd;
        Ot[kk] = ubd * vbd;
        Oa[kk] = 0.0f;
    }

    // interior + deaths (row-panel, 16B-packed stores per 4-col group)
    {
        const float ur = u_f[myrow];
        const bool rv = (myrow < nt);
        int has = 0;
        #pragma unroll
        for (int t = 0; t < 8; ++t) {
            const int cb = 32 * t + 8 * lk;
            const f32x4 va  = *reinterpret_cast<const f32x4*>(&v_f[cb]);
            const f32x4 vb  = *reinterpret_cast<const f32x4*>(&v_f[cb + 4]);
            const f32x4 ca  = *reinterpret_cast<const f32x4*>(&cm_s[cb]);
            const f32x4 cb4 = *reinterpret_cast<const f32x4*>(&cm_s[cb + 4]);
            float tvs[8];
            float abs_[8];
            #pragma unroll
            for (int j = 0; j < 4; ++j) {
                const float tv = ur * bf2f(KA[t][j]) * va[j];
                const bool bit = rv && ((cb + j) < nd) && (tv == rm) && (tv == ca[j]);
                tvs[j] = tv; abs_[j] = bit ? 1.0f : 0.0f;
                has |= bit ? 1 : 0;
            }
            #pragma unroll
            for (int j = 0; j < 4; ++j) {
                const float tv = ur * bf2f(KA[t][4 + j]) * vb[j];
                const bool bit = rv && ((cb + 4 + j) < nd) && (tv == rm) && (tv == cb4[j]);
                tvs[4 + j] = tv; abs_[4 + j] = bit ? 1.0f : 0.0f;
                has |= bit ? 1 : 0;
            }
            if (rv) {
                float* OtR = Ot + (size_t)myrow * stride;
                float* OaR = Oa + (size_t)myrow * stride;
                #pragma unroll
                for (int g = 0; g < 2; ++g) {
                    const int c0 = cb + 4 * g;
                    if (c0 + 3 < nd) {
                        F4 ot = {tvs[4*g], tvs[4*g+1], tvs[4*g+2], tvs[4*g+3]};
                        F4 oa = {abs_[4*g], abs_[4*g+1], abs_[4*g+2], abs_[4*g+3]};
                        *reinterpret_cast<F4*>(OtR + c0) = ot;
                        *reinterpret_cast<F4*>(OaR + c0) = oa;
                    } else {
                        #pragma unroll
                        for (int j = 0; j < 4; ++j) {
                            if (c0 + j < nd) {
                                OtR[c0 + j] = tvs[4*g + j];
                                OaR[c0 + j] = abs_[4*g + j];
                            }
                        }
                    }
                }
            }
        }
        has = swz16_ori(has);
        has |= __shfl_xor(has, 32, 64);
        if (lk == 0 && rv) {
            const int kk = myrow * stride + nd;
            Ot[kk] = ur * vbd;
            Oa[kk] = has ? 0.0f : 1.0f;
        }
    }

    // zero-fill padding [length, L_FLAT)
    const int length = (nt + 1) * stride;
    for (int k = length + tid; k < L_FLAT; k += 1024) {
        Ot[k] = 0.0f;
        Oa[k] = 0.0f;
    }
}

extern "C" void kernel_launch(void* const* d_in, const int* in_sizes, int n_in,
                              void* d_out, int out_size, void* d_ws, size_t ws_size,
                              hipStream_t stream)
{
    const float* aff  = (const float*)d_in[0];
    const int*   ndet = (const int*)d_in[1];
    const int*   ntrk = (const int*)d_in[2];
    const int    Bn   = in_sizes[1];
    float* out_t = (float*)d_out;
    float* out_a = out_t + (size_t)Bn * L_FLAT;
    assoc_sinkhorn_kernel<<<dim3(Bn), dim3(1024), 0, stream>>>(aff, ndet, ntrk, out_t, out_a);
}

// Round 13
// 386.247 us; speedup vs baseline: 1.7297x; 1.0159x over previous
//
#include <hip/hip_runtime.h>

// AssociationLayer: masked Sinkhorn (100 iters) + mutual-argmax assignment.
// R18 = R17 (= R13, verified best 255 us) + MFMA chain split (ILP probe).
//  R17 confirmed reproducibility (255.4/255.8 across rounds, 0.2% noise).
//  Evidence-closed levers: >64-Vreg K panels spill (R7/R10/R11); AGPR
//  residency copies/spills (R15/R16); VALU dir2 loses (R14); fp8 u/v range
//  fails (u spans ~1e-7..1 > e4m3); 2 barriers/iter is the bipartite
//  minimum; cross-wave sums already one atomic.
//  Last open hypothesis: the 8-deep serially-chained MFMA accumulator
//  (8 x ~17 cyc dependent latency, barrier-lockstep => only ~3.5 waves/SIMD
//  to interleave) is on the critical path. R18 splits each chain into two
//  independent 4-deep chains (even/odd t), combined before the rcp.
//  +4-8 transient VGPRs: 128-unified cap allows arch 64->72 at 4 waves/SIMD
//  without occupancy loss; spill tripwire = WRITE_SIZE.
//  Neutral result (+-1%) closes the latency hypothesis -> structural ceiling.
//  Epilogue reads only published u_f/v_f + identical bf16 K bits -> mutual-
//  argmax bitwise consistency unchanged. absmax ~1.0 class vs thr 4.92.

#define T_MAX   256
#define L_FLAT  (257 * 257)
#define N_ITERS 100
#define LAMBDA_F 10.0f
#define EPS_F    1e-12f

#define ROR1 0x121
#define ROR2 0x122
#define ROR4 0x124
#define ROR8 0x128

typedef short bf8   __attribute__((ext_vector_type(8)));  // 8 bf16 = 4 VGPRs
typedef float f32x4 __attribute__((ext_vector_type(4)));

struct F4 { float a, b, c, d; };   // 16B payload, 4B-aligned packed store

template<int CTRL>
__device__ __forceinline__ float dpp_addf(float x) {
    int t = __builtin_amdgcn_update_dpp(0, __float_as_int(x), CTRL, 0xF, 0xF, true);
    return x + __int_as_float(t);
}
__device__ __forceinline__ float swz16_addf(float x) {
    return x + __int_as_float(__builtin_amdgcn_ds_swizzle(__float_as_int(x), 0x401F));
}
__device__ __forceinline__ float swz16_maxf(float x) {
    return fmaxf(x, __int_as_float(__builtin_amdgcn_ds_swizzle(__float_as_int(x), 0x401F)));
}
__device__ __forceinline__ int swz16_ori(int x) {
    return x | __builtin_amdgcn_ds_swizzle(x, 0x401F);
}
__device__ __forceinline__ float fast_rcp(float x) {
#if __has_builtin(__builtin_amdgcn_rcpf)
    return __builtin_amdgcn_rcpf(x);
#else
    return 1.0f / x;
#endif
}
__device__ __forceinline__ unsigned short f2bf(float x) {   // RNE f32->bf16
    unsigned u = __float_as_uint(x);
    return (unsigned short)((u + 0x7FFFu + ((u >> 16) & 1u)) >> 16);
}
__device__ __forceinline__ float bf2f(short s) {            // exact bf16->f32
    return __uint_as_float(((unsigned)(unsigned short)s) << 16);
}

__global__ __launch_bounds__(1024, 1) void assoc_sinkhorn_kernel(
    const float* __restrict__ aff,
    const int*   __restrict__ ndet,
    const int*   __restrict__ ntrk,
    float*       __restrict__ out_t,
    float*       __restrict__ out_a)
{
    const int b   = blockIdx.x;
    const int nd  = ndet[b];
    const int nt  = ntrk[b];
    const int tid = threadIdx.x;
    const int w   = tid >> 6;     // wave 0..15 -> rows/cols 16w..16w+15
    const int l   = tid & 63;
    const int lr  = l & 15;       // m/n index within 16x16 tile
    const int lk  = l >> 4;       // k-group 0..3

    // K^T fragment-linear: [w][t][lane][8 bf16] -> 16B/lane, stride-1 b128
    __shared__ __align__(16) unsigned short KTL[16 * 8 * 64 * 8];   // 128 KB
    __shared__ __align__(16) unsigned short u_bf[256];
    __shared__ __align__(16) unsigned short v_bf[256];
    __shared__ __align__(16) float u_f[256];
    __shared__ __align__(16) float v_f[256];
    __shared__ __align__(16) float SuAcc[2];   // ping-pong cross-wave sums
    __shared__ __align__(16) float SvAcc[2];
    __shared__ __align__(16) float rm_s[256];
    __shared__ __align__(16) float cm_s[256];

    const float ndf = (float)nd;
    const float ntf = (float)nt;

    // ---------------- prologue: build bf16 K fragments ----------------
    bf8 KA[8];   // row-panel (A-op): row 16w+lr, cols 32t+8lk+j
    const float* Ab = aff + (size_t)b * (T_MAX * T_MAX);

    const int myrow = 16 * w + lr;
    const int mycol = 16 * w + lr;
    unsigned short* myKTL = &KTL[(size_t)(w * 8 * 64 + l) * 8];   // + t*512

    {
        const bool rv = (myrow < nt);
        const float* rp = Ab + (size_t)myrow * T_MAX;
        #pragma unroll
        for (int t = 0; t < 8; ++t) {
            const int c0 = 32 * t + 8 * lk;
            const float4 x0 = *reinterpret_cast<const float4*>(rp + c0);
            const float4 x1 = *reinterpret_cast<const float4*>(rp + c0 + 4);
            const float e[8] = {x0.x, x0.y, x0.z, x0.w, x1.x, x1.y, x1.z, x1.w};
            bf8 kk;
            #pragma unroll
            for (int j = 0; j < 8; ++j) {
                const float val = (rv && (c0 + j) < nd) ? __expf(LAMBDA_F * e[j]) : 0.0f;
                kk[j] = (short)f2bf(val);
            }
            KA[t] = kk;
        }
    }
    {
        // col-panel (B-op): col 16w+lr, rows 32t+8lk+j -> straight to LDS
        const bool cv = (mycol < nd);
        #pragma unroll
        for (int t = 0; t < 8; ++t) {
            const int r0 = 32 * t + 8 * lk;
            bf8 kk;
            #pragma unroll
            for (int j = 0; j < 8; ++j) {
                const float x = Ab[(size_t)(r0 + j) * T_MAX + mycol];
                const float val = (cv && (r0 + j) < nt) ? __expf(LAMBDA_F * x) : 0.0f;
                kk[j] = (short)f2bf(val);
            }
            *reinterpret_cast<bf8*>(myKTL + t * 512) = kk;   // lane-linear b128
        }
    }

    if (tid < 256) v_bf[tid] = (tid < nd) ? f2bf(1.0f) : (unsigned short)0;
    if (tid == 0) {
        SuAcc[0] = 0.0f; SuAcc[1] = 0.0f;
        SvAcc[0] = ndf;  SvAcc[1] = 0.0f;   // initial Sv = nd (v=1 on valid cols)
    }
    __syncthreads();

    float vbd = 1.0f;   // v[nd]
    float ubd = 0.0f;   // u[nt]

    const int r_a0 = 16 * w + 4 * lk;   // base row of this lane's acc quad
    float u4[4] = {0.f, 0.f, 0.f, 0.f};
    float v0 = 0.0f;

    // loop-invariant validity masks (mul instead of cmp+cndmask in loop)
    float rvm[4];
    #pragma unroll
    for (int q = 0; q < 4; ++q) rvm[q] = ((r_a0 + q) < nt) ? 1.0f : 0.0f;
    const float cvm = (mycol < nd) ? 1.0f : 0.0f;

    // ---------------- Sinkhorn iterations ----------------
    for (int it = 0; it < N_ITERS; ++it) {
        const int p = it & 1;
        const float Sv = SvAcc[p];   // broadcast read; consumed below (slack)

        // ---- dir1: p = K @ v -- TWO independent 4-deep MFMA chains ----
        f32x4 accA = {0.0f, 0.0f, 0.0f, 0.0f};
        f32x4 accB = {0.0f, 0.0f, 0.0f, 0.0f};
        #pragma unroll
        for (int t = 0; t < 4; ++t) {
            const bf8 VFa = *reinterpret_cast<const bf8*>(&v_bf[32 * (2 * t)     + 8 * lk]);
            const bf8 VFb = *reinterpret_cast<const bf8*>(&v_bf[32 * (2 * t + 1) + 8 * lk]);
            accA = __builtin_amdgcn_mfma_f32_16x16x32_bf16(KA[2 * t],     VFa, accA, 0, 0, 0);
            accB = __builtin_amdgcn_mfma_f32_16x16x32_bf16(KA[2 * t + 1], VFb, accB, 0, 0, 0);
        }

        const float vbdE = vbd + EPS_F;
        #pragma unroll
        for (int q = 0; q < 4; ++q)
            u4[q] = rvm[q] * fast_rcp((accA[q] + accB[q]) + vbdE);

        // wave Sigma(u): sum 4 quads, fold lk groups (x16, x32), one atomic
        {
            float su = (u4[0] + u4[1]) + (u4[2] + u4[3]);
            su = swz16_addf(su);
            su += __shfl_xor(su, 32, 64);
            if (l == 0) atomicAdd(&SuAcc[p], su);
        }
        if (tid == 0) SuAcc[p ^ 1] = 0.0f;   // stale slot: last read prev iter

        // publish u as bf16; writers: lr==0 lanes (4 rows each)
        if (lr == 0) {
            const unsigned p01 = (unsigned)f2bf(u4[0]) | ((unsigned)f2bf(u4[1]) << 16);
            const unsigned p23 = (unsigned)f2bf(u4[2]) | ((unsigned)f2bf(u4[3]) << 16);
            *reinterpret_cast<uint2*>(&u_bf[r_a0]) = uint2{p01, p23};
        }
        __syncthreads();   // barrier A: u + SuAcc[p] published

        const float Su = SuAcc[p];   // one broadcast read
        const float ubd_new = ndf * fast_rcp(Sv + vbd + EPS_F);
        const float vbd_new = ntf * fast_rcp(Su + ubd_new + EPS_F);

        // ---- dir2: q = K^T @ u -- TWO independent 4-deep MFMA chains ----
        f32x4 qaA = {0.0f, 0.0f, 0.0f, 0.0f};
        f32x4 qaB = {0.0f, 0.0f, 0.0f, 0.0f};
        #pragma unroll
        for (int t = 0; t < 4; ++t) {
            const bf8 UFa = *reinterpret_cast<const bf8*>(&u_bf[32 * (2 * t)     + 8 * lk]);
            const bf8 UFb = *reinterpret_cast<const bf8*>(&u_bf[32 * (2 * t + 1) + 8 * lk]);
            const bf8 kba = *reinterpret_cast<const bf8*>(myKTL + (2 * t)     * 512);
            const bf8 kbb = *reinterpret_cast<const bf8*>(myKTL + (2 * t + 1) * 512);
            qaA = __builtin_amdgcn_mfma_f32_16x16x32_bf16(UFa, kba, qaA, 0, 0, 0);
            qaB = __builtin_amdgcn_mfma_f32_16x16x32_bf16(UFb, kbb, qaB, 0, 0, 0);
        }

        const float ubdE = ubd_new + EPS_F;
        v0 = cvm * fast_rcp((qaA[0] + qaB[0]) + ubdE);

        // wave Sigma(v) over its 16 cols (varies over lr): DPP fold + atomic
        {
            float sv = v0;
            sv = dpp_addf<ROR1>(sv);
            sv = dpp_addf<ROR2>(sv);
            sv = dpp_addf<ROR4>(sv);
            sv = dpp_addf<ROR8>(sv);
            if (l == 0) atomicAdd(&SvAcc[p ^ 1], sv);
        }
        if (tid == 0) SvAcc[p] = 0.0f;   // stale slot: last read this dir1
        if (lk == 0) v_bf[mycol] = f2bf(v0);
        ubd = ubd_new;
        vbd = vbd_new;
        __syncthreads();   // barrier B: v + SvAcc[p^1] published
    }

    // ---- publish final u, v in f32 for the epilogue ----
    if (lr == 0) {
        f32x4 uf = {u4[0], u4[1], u4[2], u4[3]};
        *reinterpret_cast<f32x4*>(&u_f[r_a0]) = uf;
    }
    if (lk == 0) v_f[mycol] = v0;
    __syncthreads();

    // ================= epilogue =================
    // T = (u*k)*v with identical mul order on both panels -> bitwise-
    // consistent equality tests for mutual argmax.
    float rm;   // rowmax of this lane's row
    {
        const float ur = u_f[myrow];
        float mm = 0.0f;
        #pragma unroll
        for (int t = 0; t < 8; ++t) {
            const f32x4 va = *reinterpret_cast<const f32x4*>(&v_f[32 * t + 8 * lk]);
            const f32x4 vb = *reinterpret_cast<const f32x4*>(&v_f[32 * t + 8 * lk + 4]);
            const float vj[8] = {va[0], va[1], va[2], va[3], vb[0], vb[1], vb[2], vb[3]};
            #pragma unroll
            for (int j = 0; j < 8; ++j) {
                const float tv = ur * bf2f(KA[t][j]) * vj[j];
                mm = fmaxf(mm, tv);
            }
        }
        mm = swz16_maxf(mm);
        mm = fmaxf(mm, __shfl_xor(mm, 32, 64));
        rm = mm;
        if (lk == 0) rm_s[myrow] = mm;
    }
    float cmv;  // colmax of this lane's col
    {
        const float vc = v_f[mycol];
        float mm = 0.0f;
        #pragma unroll
        for (int t = 0; t < 8; ++t) {
            const int rb = 32 * t + 8 * lk;
            const bf8 kb = *reinterpret_cast<const bf8*>(myKTL + t * 512);
            const f32x4 ua = *reinterpret_cast<const f32x4*>(&u_f[rb]);
            const f32x4 ub = *reinterpret_cast<const f32x4*>(&u_f[rb + 4]);
            const float uj[8] = {ua[0], ua[1], ua[2], ua[3], ub[0], ub[1], ub[2], ub[3]};
            #pragma unroll
            for (int j = 0; j < 8; ++j) {
                const float tv = uj[j] * bf2f(kb[j]) * vc;
                mm = fmaxf(mm, tv);
            }
        }
        mm = swz16_maxf(mm);
        mm = fmaxf(mm, __shfl_xor(mm, 32, 64));
        cmv = mm;
        if (lk == 0) cm_s[mycol] = mm;
    }
    __syncthreads();   // rm_s / cm_s published

    float* Ot = out_t + (size_t)b * L_FLAT;
    float* Oa = out_a + (size_t)b * L_FLAT;
    const int stride = nd + 1;

    // births row (col-panel: col-has + write) + corner
    {
        const float vc = v_f[mycol];
        const bool cv = (mycol < nd);
        int has = 0;
        #pragma unroll
        for (int t = 0; t < 8; ++t) {
            const int rb = 32 * t + 8 * lk;
            const bf8 kb = *reinterpret_cast<const bf8*>(myKTL + t * 512);
            const f32x4 ua = *reinterpret_cast<const f32x4*>(&u_f[rb]);
            const f32x4 ub = *reinterpret_cast<const f32x4*>(&u_f[rb + 4]);
            const f32x4 ra = *reinterpret_cast<const f32x4*>(&rm_s[rb]);
            const f32x4 rb4 = *reinterpret_cast<const f32x4*>(&rm_s[rb + 4]);
            const float uj[8] = {ua[0], ua[1], ua[2], ua[3], ub[0], ub[1], ub[2], ub[3]};
            const float rj[8] = {ra[0], ra[1], ra[2], ra[3], rb4[0], rb4[1], rb4[2], rb4[3]};
            #pragma unroll
            for (int j = 0; j < 8; ++j) {
                const int rowj = rb + j;
                const float tv = uj[j] * bf2f(kb[j]) * vc;
                const bool bit = (rowj < nt) && cv && (tv == rj[j]) && (tv == cmv);
                has |= bit ? 1 : 0;
            }
        }
        has = swz16_ori(has);
        has |= __shfl_xor(has, 32, 64);
        if (lk == 0 && cv) {
            const int kk = nt * stride + mycol;
            Ot[kk] = ubd * vc;
            Oa[kk] = has ? 0.0f : 1.0f;
        }
    }
    if (tid == 0) {
        const int kk = nt * stride + nd;
        Ot[kk] = ubd * vbd;
        Oa[kk] = 0.0f;
    }

    // interior + deaths (row-panel, 16B-packed stores per 4-col group)
    {
        const float ur = u_f[myrow];
        const bool rv = (myrow < nt);
        int has = 0;
        #pragma unroll
        for (int t = 0; t < 8; ++t) {
            const int cb = 32 * t + 8 * lk;
            const f32x4 va  = *reinterpret_cast<const f32x4*>(&v_f[cb]);
            const f32x4 vb  = *reinterpret_cast<const f32x4*>(&v_f[cb + 4]);
            const f32x4 ca  = *reinterpret_cast<const f32x4*>(&cm_s[cb]);
            const f32x4 cb4 = *reinterpret_cast<const f32x4*>(&cm_s[cb + 4]);
            float tvs[8];
            float abs_[8];
            #pragma unroll
            for (int j = 0; j < 4; ++j) {
                const float tv = ur * bf2f(KA[t][j]) * va[j];
                const bool bit = rv && ((cb + j) < nd) && (tv == rm) && (tv == ca[j]);
                tvs[j] = tv; abs_[j] = bit ? 1.0f : 0.0f;
                has |= bit ? 1 : 0;
            }
            #pragma unroll
            for (int j = 0; j < 4; ++j) {
                const float tv = ur * bf2f(KA[t][4 + j]) * vb[j];
                const bool bit = rv && ((cb + 4 + j) < nd) && (tv == rm) && (tv == cb4[j]);
                tvs[4 + j] = tv; abs_[4 + j] = bit ? 1.0f : 0.0f;
                has |= bit ? 1 : 0;
            }
            if (rv) {
                float* OtR = Ot + (size_t)myrow * stride;
                float* OaR = Oa + (size_t)myrow * stride;
                #pragma unroll
                for (int g = 0; g < 2; ++g) {
                    const int c0 = cb + 4 * g;
                    if (c0 + 3 < nd) {
                        F4 ot = {tvs[4*g], tvs[4*g+1], tvs[4*g+2], tvs[4*g+3]};
                        F4 oa = {abs_[4*g], abs_[4*g+1], abs_[4*g+2], abs_[4*g+3]};
                        *reinterpret_cast<F4*>(OtR + c0) = ot;
                        *reinterpret_cast<F4*>(OaR + c0) = oa;
                    } else {
                        #pragma unroll
                        for (int j = 0; j < 4; ++j) {
                            if (c0 + j < nd) {
                                OtR[c0 + j] = tvs[4*g + j];
                                OaR[c0 + j] = abs_[4*g + j];
                            }
                        }
                    }
                }
            }
        }
        has = swz16_ori(has);
        has |= __shfl_xor(has, 32, 64);
        if (lk == 0 && rv) {
            const int kk = myrow * stride + nd;
            Ot[kk] = ur * vbd;
            Oa[kk] = has ? 0.0f : 1.0f;
        }
    }

    // zero-fill padding [length, L_FLAT)
    const int length = (nt + 1) * stride;
    for (int k = length + tid; k < L_FLAT; k += 1024) {
        Ot[k] = 0.0f;
        Oa[k] = 0.0f;
    }
}

extern "C" void kernel_launch(void* const* d_in, const int* in_sizes, int n_in,
                              void* d_out, int out_size, void* d_ws, size_t ws_size,
                              hipStream_t stream)
{
    const float* aff  = (const float*)d_in[0];
    const int*   ndet = (const int*)d_in[1];
    const int*   ntrk = (const int*)d_in[2];
    const int    Bn   = in_sizes[1];
    float* out_t = (float*)d_out;
    float* out_a = out_t + (size_t)Bn * L_FLAT;
    assoc_sinkhorn_kernel<<<dim3(Bn), dim3(1024), 0, stream>>>(aff, ndet, ntrk, out_t, out_a);
}